// Round 9
// baseline (290.031 us; speedup 1.0000x reference)
//
#include <hip/hip_runtime.h>

typedef float floatx4 __attribute__((ext_vector_type(4)));
typedef short s16x8 __attribute__((ext_vector_type(8)));  // 8 bf16 (4 VGPRs)

#define WG 256
#define NBUCK 1024  // buckets of 128 nodes -> covers N <= 131072 (here N=100000)
#define BSH 7       // 128 nodes per bucket
#define EBLK 512    // blocks for the edge-build half of k_main
#define CAP 4096    // per-bucket capacity; uniform-random mean ~2046, sigma ~45
#define MAXIT 16    // per-thread cached edges; covers chunk <= 4096 (E <= 2M)

__device__ inline unsigned pack_bf16_rne(float a, float b) {
    unsigned ua = __float_as_uint(a), ub = __float_as_uint(b);
    ua = (ua + 0x7FFFu + ((ua >> 16) & 1u)) >> 16;
    ub = (ub + 0x7FFFu + ((ub >> 16) & 1u)) >> 16;
    return ua | (ub << 16);
}

union FragU {
    unsigned u[4];
    uint4 q;
    s16x8 v;
};

// ---------------------------------------------------------------------------
// One-time: pack W (256x64 f32) into MFMA B-fragment bf16 layout (2048 uint4,
// 32 KB); zero the bucket cursors (unpadded - R7 proved padded cursors cost
// cold-line fetches on the atomic path) and the per-node in-degree array.
__global__ __launch_bounds__(WG) void k_packw(const float* __restrict__ W,
                                              uint4* __restrict__ wpack,
                                              int* __restrict__ cursor,
                                              int* __restrict__ deg, int N) {
    const int q = blockIdx.x * WG + threadIdx.x;  // 64 blocks -> 16384 threads
    if (q < NBUCK) cursor[q] = 0;
    for (int z = q; z < N; z += 16384) deg[z] = 0;
    if (q < 2048) {
        const int kb = q >> 8, nt = (q >> 6) & 3, ln = q & 63;
        const int quad = ln >> 4, l15 = ln & 15;
        const int col = nt * 16 + l15;
        const int krow = kb * 32 + quad * 8;
        unsigned up[4];
#pragma unroll
        for (int p = 0; p < 4; p++) {
            float a = W[(krow + 2 * p) * 64 + col];
            float b2 = W[(krow + 2 * p + 1) * 64 + col];
            up[p] = pack_bf16_rne(a, b2);
        }
        uint4 pk = {up[0], up[1], up[2], up[3]};
        wpack[q] = pk;
    }
}

// ---------------------------------------------------------------------------
// Fused: blocks [0, EBLK) bucket the edges (register-cached two-pass) AND
// count per-node in-degree (global atomics - R6 measured this ~free); blocks
// [EBLK, EBLK+gemmB) run the MFMA gemm. The halves are independent, so they
// overlap inside one dispatch (un-fusing cost ~15 us in R4). GEMM branch is
// the R3 variant (C++ x loads + keep-alive, best measured 68.5 us).
__global__ __launch_bounds__(WG, 4) void k_main(const void* __restrict__ ei, int* __restrict__ cursor,
                                                unsigned* __restrict__ ebuf, int* __restrict__ deg, int E,
                                                const float* __restrict__ x, const uint4* __restrict__ wpack,
                                                unsigned short* __restrict__ g, int N) {
    __shared__ int hh[NBUCK];
    __shared__ int hbase[NBUCK];
    __shared__ int s32flag;
    const int t = threadIdx.x;

    if ((int)blockIdx.x < EBLK) {
        // ---------------- edge-bucket branch ----------------
        if (t == 0) s32flag = 0;
        for (int i = t; i < NBUCK; i += WG) hh[i] = 0;
        __syncthreads();
        {
            const int* w = (const int*)ei;
            int nz = 0;
            for (int j = t; j < 4096; j += WG) nz |= (w[2 * j + 1] != 0);
            if (nz) atomicOr(&s32flag, 1);
        }
        __syncthreads();
        const bool i32 = (s32flag != 0);
        const int chunk = (E + EBLK - 1) / EBLK;
        const int s = blockIdx.x * chunk;
        const int eend = min(E, s + chunk);

        if (chunk <= MAXIT * WG) {
            // Register-cached two-pass: edges read from HBM exactly once.
            unsigned ew[MAXIT];
            unsigned short ebk[MAXIT];
#pragma unroll
            for (int i = 0; i < MAXIT; i++) {
                const int e = s + t + i * WG;
                ebk[i] = 0xFFFFu;
                if (e < eend) {
                    int sN, dN;
                    if (i32) {
                        const int* p = (const int*)ei;
                        sN = p[e];
                        dN = p[E + e];
                    } else {
                        const long long* p = (const long long*)ei;
                        sN = (int)p[e];
                        dN = (int)p[(long long)E + e];
                    }
                    ew[i] = (unsigned)sN | ((unsigned)(dN & 127) << 24);
                    ebk[i] = (unsigned short)(dN >> BSH);
                    atomicAdd(&hh[dN >> BSH], 1);
                    atomicAdd(&deg[dN], 1);  // global in-degree
                }
            }
            __syncthreads();
            for (int i = t; i < NBUCK; i += WG) {
                int c = hh[i];
                hbase[i] = c ? atomicAdd(&cursor[i], c) : 0;
                hh[i] = 0;  // reuse as local cursor
            }
            __syncthreads();
#pragma unroll
            for (int i = 0; i < MAXIT; i++) {
                if (ebk[i] != 0xFFFFu) {
                    const int bkt = ebk[i];
                    const int pos = hbase[bkt] + atomicAdd(&hh[bkt], 1);
                    if (pos < CAP) ebuf[(size_t)bkt * CAP + pos] = ew[i];
                }
            }
        } else {
            // Fallback for E too large for the register cache: classic 2-pass.
            if (i32) {
                const int* pd = (const int*)ei + E;
                for (int e = s + t; e < eend; e += WG) {
                    const int dN = pd[e];
                    atomicAdd(&hh[dN >> BSH], 1);
                    atomicAdd(&deg[dN], 1);
                }
            } else {
                const long long* pd = (const long long*)ei + E;
                for (int e = s + t; e < eend; e += WG) {
                    const int dN = (int)pd[e];
                    atomicAdd(&hh[dN >> BSH], 1);
                    atomicAdd(&deg[dN], 1);
                }
            }
            __syncthreads();
            for (int i = t; i < NBUCK; i += WG) {
                int c = hh[i];
                hbase[i] = c ? atomicAdd(&cursor[i], c) : 0;
                hh[i] = 0;
            }
            __syncthreads();
            for (int e = s + t; e < eend; e += WG) {
                int sN, dN;
                if (i32) {
                    const int* p = (const int*)ei;
                    sN = p[e];
                    dN = p[E + e];
                } else {
                    const long long* p = (const long long*)ei;
                    sN = (int)p[e];
                    dN = (int)p[(long long)E + e];
                }
                int bkt = dN >> BSH;
                int pos = hbase[bkt] + atomicAdd(&hh[bkt], 1);
                if (pos < CAP) ebuf[(size_t)bkt * CAP + pos] = (unsigned)sN | ((unsigned)(dN & 127) << 24);
            }
        }
    } else {
        // ---------------- GEMM branch (MFMA 16x16x32 bf16) ----------------
        const int bb = blockIdx.x - EBLK;
        const int wv = t >> 6;
        const int lane = t & 63;
        const int quad = lane >> 4, l15 = lane & 15;

        long long arow = (long long)bb * 64 + wv * 16 + l15;
        if (arow >= N) arow = N - 1;  // clamp loads; stores guarded below
        const float* xr = x + arow * 256 + quad * 8;
        const uint4* wp = wpack + lane;

        floatx4 xv[8][2];
#pragma unroll
        for (int kb = 0; kb < 8; kb++) {
            xv[kb][0] = *(const floatx4*)(xr + kb * 32);
            xv[kb][1] = *(const floatx4*)(xr + kb * 32 + 4);
        }
#pragma unroll
        for (int kb = 0; kb < 8; kb++) {
            asm volatile("" : "+v"(xv[kb][0]), "+v"(xv[kb][1]));
        }
        __builtin_amdgcn_sched_barrier(0);

        floatx4 acc[4];
#pragma unroll
        for (int nt = 0; nt < 4; nt++) acc[nt] = 0.f;

        FragU bc0, bc1, bc2, bc3;
        bc0.q = wp[0 * 64];
        bc1.q = wp[1 * 64];
        bc2.q = wp[2 * 64];
        bc3.q = wp[3 * 64];

#pragma unroll
        for (int kb = 0; kb < 8; kb++) {
            FragU bn0, bn1, bn2, bn3;
            if (kb < 7) {
                bn0.q = wp[((kb + 1) * 4 + 0) * 64];
                bn1.q = wp[((kb + 1) * 4 + 1) * 64];
                bn2.q = wp[((kb + 1) * 4 + 2) * 64];
                bn3.q = wp[((kb + 1) * 4 + 3) * 64];
            }
            FragU a;
            a.u[0] = pack_bf16_rne(xv[kb][0][0], xv[kb][0][1]);
            a.u[1] = pack_bf16_rne(xv[kb][0][2], xv[kb][0][3]);
            a.u[2] = pack_bf16_rne(xv[kb][1][0], xv[kb][1][1]);
            a.u[3] = pack_bf16_rne(xv[kb][1][2], xv[kb][1][3]);
            acc[0] = __builtin_amdgcn_mfma_f32_16x16x32_bf16(a.v, bc0.v, acc[0], 0, 0, 0);
            acc[1] = __builtin_amdgcn_mfma_f32_16x16x32_bf16(a.v, bc1.v, acc[1], 0, 0, 0);
            acc[2] = __builtin_amdgcn_mfma_f32_16x16x32_bf16(a.v, bc2.v, acc[2], 0, 0, 0);
            acc[3] = __builtin_amdgcn_mfma_f32_16x16x32_bf16(a.v, bc3.v, acc[3], 0, 0, 0);
            if (kb < 7) {
                bc0 = bn0;
                bc1 = bn1;
                bc2 = bn2;
                bc3 = bn3;
            }
        }

        const long long orow0 = (long long)bb * 64 + wv * 16 + quad * 4;
#pragma unroll
        for (int r = 0; r < 4; r++) {
            const long long orow = orow0 + r;
            if (orow < N) {
#pragma unroll
                for (int nt = 0; nt < 4; nt++) {
                    float v = acc[nt][r];  // UNscaled h
                    unsigned uv = __float_as_uint(v);
                    uv = (uv + 0x7FFFu + ((uv >> 16) & 1u)) >> 16;
                    g[orow * 64 + nt * 16 + l15] = (unsigned short)uv;
                }
            }
        }
    }
}

// ---------------------------------------------------------------------------
// Fused CSR+gather: one block per 128-node bucket. Phase A counting-sorts the
// bucket's ebuf slice into a 16 KB LDS src-list (register-cached words, one
// int LDS-atomic per edge - NOT R6's 8x f32 ds-atomics). Phase B is R8's
// proven 16-lane/even-odd gather walking the LDS lists; dinv[src] =
// rsqrtf(deg[src]+1) with the deg load prefetched beside the row. Own-node
// dinv comes from the local histogram. Eliminates srcs/off/dinv arrays
// (~27 MB traffic), the k_csr dispatch, and one launch boundary.
__global__ __launch_bounds__(WG) void k_agg(const unsigned* __restrict__ ebuf, const int* __restrict__ cursor,
                                            const int* __restrict__ deg, const unsigned short* __restrict__ g,
                                            const float* __restrict__ bias, float* __restrict__ out, int N) {
    __shared__ int slist[CAP];
    __shared__ int h[128];
    __shared__ int off[128];
    __shared__ int cur[128];
    __shared__ int ldg[128];
    const int t = threadIdx.x;
    const int b = blockIdx.x;
    const int node0 = b << BSH;

    if (t < 128) h[t] = 0;
    __syncthreads();

    const int cnt = min(cursor[b], CAP);  // cnt <= CAP = 16*WG by construction
    const unsigned* eb = ebuf + (size_t)b * CAP;

    // --- phase A: counting sort into slist (register-cached edge words) ---
    unsigned ew[16];
#pragma unroll
    for (int i = 0; i < 16; i++) {
        const int e = t + i * WG;
        ew[i] = (e < cnt) ? eb[e] : 0xFFFFFFFFu;  // valid words are < 0x80000000
        if (ew[i] != 0xFFFFFFFFu) atomicAdd(&h[(ew[i] >> 24) & 127], 1);
    }
    __syncthreads();
    if (t < 128) {
        ldg[t] = h[t];
        off[t] = h[t];
        cur[t] = 0;
    }
    __syncthreads();
    for (int d = 1; d < 128; d <<= 1) {  // inclusive scan on off
        int a = 0;
        if (t < 128 && t >= d) a = off[t - d];
        __syncthreads();
        if (t < 128) off[t] += a;
        __syncthreads();
    }
    if (t < 128) off[t] -= ldg[t];  // exclusive
    __syncthreads();
#pragma unroll
    for (int i = 0; i < 16; i++) {
        if (ew[i] != 0xFFFFFFFFu) {
            const int dl = (ew[i] >> 24) & 127;
            const int pos = off[dl] + atomicAdd(&cur[dl], 1);
            slist[pos] = (int)(ew[i] & 0xFFFFFFu);
        }
    }
    __syncthreads();

    // --- phase B: gather (16 lanes/node, even/odd edge split, 1-ahead) ---
    const int gid = t >> 4;        // 16 groups of 16 lanes
    const int sub = (t >> 3) & 1;  // 0: even local edges, 1: odd
    const int c8 = (t & 7) * 8;    // cols c8 .. c8+7
    for (int nn = gid; nn < 128; nn += 16) {
        const int node = node0 + nn;
        if (node >= N) continue;  // uniform per 16-lane group; no barriers below
        const int e0 = off[nn], ne = ldg[nn];
        float a0 = 0.f, a1 = 0.f, a2 = 0.f, a3 = 0.f, a4 = 0.f, a5 = 0.f, a6 = 0.f, a7 = 0.f;
        int j = sub;  // this half walks j, j+2, j+4, ...
        if (j < ne) {
            int s_cur = slist[e0 + j];
            int jn = j + 2;
            int s_nxt = (jn < ne) ? slist[e0 + jn] : 0;
            int dgc = deg[s_cur];
            uint4 v = *(const uint4*)(g + (size_t)s_cur * 64 + c8);
            for (;;) {
                const bool more = jn < ne;
                int dgn = 0;
                uint4 vn = v;
                int s2 = 0;
                if (more) {  // next edge's dependent loads issue under the FMAs
                    dgn = deg[s_nxt];
                    vn = *(const uint4*)(g + (size_t)s_nxt * 64 + c8);
                }
                const int jn2 = jn + 2;
                if (jn2 < ne) s2 = slist[e0 + jn2];
                const float ds = rsqrtf((float)(dgc + 1));
                a0 += ds * __uint_as_float(v.x << 16);
                a1 += ds * __uint_as_float(v.x & 0xFFFF0000u);
                a2 += ds * __uint_as_float(v.y << 16);
                a3 += ds * __uint_as_float(v.y & 0xFFFF0000u);
                a4 += ds * __uint_as_float(v.z << 16);
                a5 += ds * __uint_as_float(v.z & 0xFFFF0000u);
                a6 += ds * __uint_as_float(v.w << 16);
                a7 += ds * __uint_as_float(v.w & 0xFFFF0000u);
                if (!more) break;
                dgc = dgn;
                v = vn;
                s_nxt = s2;
                jn = jn2;
            }
        }
        // merge halves: lanes l and l^8 hold the same columns
        a0 += __shfl_xor(a0, 8, 64);
        a1 += __shfl_xor(a1, 8, 64);
        a2 += __shfl_xor(a2, 8, 64);
        a3 += __shfl_xor(a3, 8, 64);
        a4 += __shfl_xor(a4, 8, 64);
        a5 += __shfl_xor(a5, 8, 64);
        a6 += __shfl_xor(a6, 8, 64);
        a7 += __shfl_xor(a7, 8, 64);
        if (sub == 0) {
            const float d = rsqrtf((float)(ldg[nn] + 1));  // own dinv, local histogram
            const uint4 vs = *(const uint4*)(g + (size_t)node * 64 + c8);  // self row
            a0 += d * __uint_as_float(vs.x << 16);
            a1 += d * __uint_as_float(vs.x & 0xFFFF0000u);
            a2 += d * __uint_as_float(vs.y << 16);
            a3 += d * __uint_as_float(vs.y & 0xFFFF0000u);
            a4 += d * __uint_as_float(vs.z << 16);
            a5 += d * __uint_as_float(vs.z & 0xFFFF0000u);
            a6 += d * __uint_as_float(vs.w << 16);
            a7 += d * __uint_as_float(vs.w & 0xFFFF0000u);
            const floatx4 b0 = *(const floatx4*)(bias + c8);
            const floatx4 b1 = *(const floatx4*)(bias + c8 + 4);
            floatx4 o0, o1;
            o0[0] = d * a0 + b0[0];
            o0[1] = d * a1 + b0[1];
            o0[2] = d * a2 + b0[2];
            o0[3] = d * a3 + b0[3];
            o1[0] = d * a4 + b1[0];
            o1[1] = d * a5 + b1[1];
            o1[2] = d * a6 + b1[2];
            o1[3] = d * a7 + b1[3];
            *(floatx4*)(out + (size_t)node * 64 + c8) = o0;
            *(floatx4*)(out + (size_t)node * 64 + c8 + 4) = o1;
        }
    }
}

extern "C" void kernel_launch(void* const* d_in, const int* in_sizes, int n_in,
                              void* d_out, int out_size, void* d_ws, size_t ws_size,
                              hipStream_t stream) {
    const float* x = (const float*)d_in[0];
    const void* ei = d_in[1];
    const float* W = (const float*)d_in[2];
    const float* b = (const float*)d_in[3];
    float* out = (float*)d_out;

    const int N = in_sizes[0] / 256;  // requires N < 2^24 and N <= 131072 (here 100000)
    const int E = in_sizes[1] / 2;
    const int NBUSE = (N + 127) >> BSH;       // 782 buckets used
    const int GEMMB = (N + 63) / 64;          // 1563 gemm blocks

    char* ws = (char*)d_ws;
    size_t o = 0;
    auto alloc = [&](size_t bytes) -> void* {
        void* p = ws + o;
        o += (bytes + 255) & ~(size_t)255;
        return p;
    };
    unsigned short* g = (unsigned short*)alloc((size_t)N * 64 * 2);   // bf16 h, 12.8 MB
    unsigned* ebuf = (unsigned*)alloc((size_t)NBUCK * CAP * 4);       // bucketed edges, 16.8 MB
    int* cursor = (int*)alloc((size_t)NBUCK * 4);                     // unpadded
    int* deg = (int*)alloc((size_t)N * 4);                            // per-node in-degree
    uint4* wpack = (uint4*)alloc((size_t)2048 * 16);                  // frag-layout bf16 W, 32 KB
    if (o > ws_size) return;  // fail visibly rather than corrupt

    k_packw<<<64, WG, 0, stream>>>(W, wpack, cursor, deg, N);
    k_main<<<EBLK + GEMMB, WG, 0, stream>>>(ei, cursor, ebuf, deg, E, x, wpack, g, N);
    k_agg<<<NBUSE, WG, 0, stream>>>(ebuf, cursor, deg, g, b, out, N);
}

// Round 10
// 243.534 us; speedup vs baseline: 1.1909x; 1.1909x over previous
//
#include <hip/hip_runtime.h>

typedef float floatx4 __attribute__((ext_vector_type(4)));
typedef short s16x8 __attribute__((ext_vector_type(8)));  // 8 bf16 (4 VGPRs)

#define WG 256
#define NBUCK 512   // buckets of 256 nodes -> covers N <= 131072 (here N=100000)
#define BSH 8       // 256 nodes per bucket
#define EBLK 512    // blocks for the edge-build half of k_main
#define CAP 8192    // per-bucket capacity; uniform-random mean 4092, sigma 64
#define MAXIT 16    // per-thread cached edges; covers chunk <= 4096 (E <= 2M)

__device__ inline unsigned pack_bf16_rne(float a, float b) {
    unsigned ua = __float_as_uint(a), ub = __float_as_uint(b);
    ua = (ua + 0x7FFFu + ((ua >> 16) & 1u)) >> 16;
    ub = (ub + 0x7FFFu + ((ub >> 16) & 1u)) >> 16;
    return ua | (ub << 16);
}

union FragU {
    unsigned u[4];
    uint4 q;
    s16x8 v;
};

// ---------------------------------------------------------------------------
// One-time: pack W (256x64 f32) into MFMA B-fragment bf16 layout (2048 uint4,
// 32 KB). GEMM blocks read fragments straight from this buffer (L2-hot,
// coalesced 1 KB/wave loads). Also zeroes the bucket cursors (unpadded -
// R7 proved padded cursors cost cold-line fetches on the atomic path).
// R9 NOTE: 1024 buckets of 128 regressed k_main 68.5 -> 112.5 us (WRITE_SIZE
// 26 -> 77 MB: per-block per-bucket runs shrink to ~3 edges -> partial-line
// write amplification on ebuf). 512 buckets of 256 is the measured optimum.
__global__ __launch_bounds__(WG) void k_packw(const float* __restrict__ W,
                                              uint4* __restrict__ wpack,
                                              int* __restrict__ cursor) {
    const int q = blockIdx.x * WG + threadIdx.x;  // [0, 2048)
    if (q < NBUCK) cursor[q] = 0;
    const int kb = q >> 8, nt = (q >> 6) & 3, ln = q & 63;
    const int quad = ln >> 4, l15 = ln & 15;
    const int col = nt * 16 + l15;
    const int krow = kb * 32 + quad * 8;
    unsigned up[4];
#pragma unroll
    for (int p = 0; p < 4; p++) {
        float a = W[(krow + 2 * p) * 64 + col];
        float b2 = W[(krow + 2 * p + 1) * 64 + col];
        up[p] = pack_bf16_rne(a, b2);
    }
    uint4 pk = {up[0], up[1], up[2], up[3]};
    wpack[q] = pk;
}

// ---------------------------------------------------------------------------
// Fused: blocks [0, EBLK) bucket the edges (register-cached two-pass), blocks
// [EBLK, EBLK+gemmB) run the MFMA gemm. The halves are independent, so they
// overlap inside one dispatch (un-fusing cost ~15 us in R4). GEMM branch is
// the R3 variant (C++ x loads + keep-alive): the R5 inline-asm vmcnt(0)
// drain serialized x against the B stream and regressed 68.5 -> 79.
__global__ __launch_bounds__(WG, 4) void k_main(const void* __restrict__ ei, int* __restrict__ cursor,
                                                unsigned* __restrict__ ebuf, int E,
                                                const float* __restrict__ x, const uint4* __restrict__ wpack,
                                                unsigned short* __restrict__ g, int N) {
    __shared__ int hh[NBUCK];
    __shared__ int hbase[NBUCK];
    __shared__ int s32flag;
    const int t = threadIdx.x;

    if ((int)blockIdx.x < EBLK) {
        // ---------------- edge-bucket branch ----------------
        if (t == 0) s32flag = 0;
        for (int i = t; i < NBUCK; i += WG) hh[i] = 0;
        __syncthreads();
        {
            const int* w = (const int*)ei;
            int nz = 0;
            for (int j = t; j < 4096; j += WG) nz |= (w[2 * j + 1] != 0);
            if (nz) atomicOr(&s32flag, 1);
        }
        __syncthreads();
        const bool i32 = (s32flag != 0);
        const int chunk = (E + EBLK - 1) / EBLK;
        const int s = blockIdx.x * chunk;
        const int eend = min(E, s + chunk);

        if (chunk <= MAXIT * WG) {
            // Register-cached two-pass: edges read from HBM exactly once.
            unsigned ew[MAXIT];
            unsigned short ebk[MAXIT];
#pragma unroll
            for (int i = 0; i < MAXIT; i++) {
                const int e = s + t + i * WG;
                ebk[i] = 0xFFFFu;
                if (e < eend) {
                    int sN, dN;
                    if (i32) {
                        const int* p = (const int*)ei;
                        sN = p[e];
                        dN = p[E + e];
                    } else {
                        const long long* p = (const long long*)ei;
                        sN = (int)p[e];
                        dN = (int)p[(long long)E + e];
                    }
                    ew[i] = (unsigned)sN | ((unsigned)(dN & 255) << 24);
                    ebk[i] = (unsigned short)(dN >> BSH);
                    atomicAdd(&hh[dN >> BSH], 1);
                }
            }
            __syncthreads();
            for (int i = t; i < NBUCK; i += WG) {
                int c = hh[i];
                hbase[i] = c ? atomicAdd(&cursor[i], c) : 0;
                hh[i] = 0;  // reuse as local cursor
            }
            __syncthreads();
#pragma unroll
            for (int i = 0; i < MAXIT; i++) {
                if (ebk[i] != 0xFFFFu) {
                    const int bkt = ebk[i];
                    const int pos = hbase[bkt] + atomicAdd(&hh[bkt], 1);
                    if (pos < CAP) ebuf[(size_t)bkt * CAP + pos] = ew[i];
                }
            }
        } else {
            // Fallback for E too large for the register cache: classic 2-pass.
            if (i32) {
                const int* pd = (const int*)ei + E;
                for (int e = s + t; e < eend; e += WG) atomicAdd(&hh[pd[e] >> BSH], 1);
            } else {
                const long long* pd = (const long long*)ei + E;
                for (int e = s + t; e < eend; e += WG) atomicAdd(&hh[(int)pd[e] >> BSH], 1);
            }
            __syncthreads();
            for (int i = t; i < NBUCK; i += WG) {
                int c = hh[i];
                hbase[i] = c ? atomicAdd(&cursor[i], c) : 0;
                hh[i] = 0;
            }
            __syncthreads();
            for (int e = s + t; e < eend; e += WG) {
                int sN, dN;
                if (i32) {
                    const int* p = (const int*)ei;
                    sN = p[e];
                    dN = p[E + e];
                } else {
                    const long long* p = (const long long*)ei;
                    sN = (int)p[e];
                    dN = (int)p[(long long)E + e];
                }
                int bkt = dN >> BSH;
                int pos = hbase[bkt] + atomicAdd(&hh[bkt], 1);
                if (pos < CAP) ebuf[(size_t)bkt * CAP + pos] = (unsigned)sN | ((unsigned)(dN & 255) << 24);
            }
        }
    } else {
        // ---------------- GEMM branch (MFMA 16x16x32 bf16) ----------------
        // R3 variant (best measured): C++ x loads + keep-alive, B fragments
        // depth-1 prefetched from L2-hot wpack. No LDS use, no barriers.
        const int bb = blockIdx.x - EBLK;
        const int wv = t >> 6;
        const int lane = t & 63;
        const int quad = lane >> 4, l15 = lane & 15;

        long long arow = (long long)bb * 64 + wv * 16 + l15;
        if (arow >= N) arow = N - 1;  // clamp loads; stores guarded below
        const float* xr = x + arow * 256 + quad * 8;
        const uint4* wp = wpack + lane;

        floatx4 xv[8][2];
#pragma unroll
        for (int kb = 0; kb < 8; kb++) {
            xv[kb][0] = *(const floatx4*)(xr + kb * 32);
            xv[kb][1] = *(const floatx4*)(xr + kb * 32 + 4);
        }
#pragma unroll
        for (int kb = 0; kb < 8; kb++) {
            asm volatile("" : "+v"(xv[kb][0]), "+v"(xv[kb][1]));
        }
        __builtin_amdgcn_sched_barrier(0);

        floatx4 acc[4];
#pragma unroll
        for (int nt = 0; nt < 4; nt++) acc[nt] = 0.f;

        FragU bc0, bc1, bc2, bc3;
        bc0.q = wp[0 * 64];
        bc1.q = wp[1 * 64];
        bc2.q = wp[2 * 64];
        bc3.q = wp[3 * 64];

#pragma unroll
        for (int kb = 0; kb < 8; kb++) {
            FragU bn0, bn1, bn2, bn3;
            if (kb < 7) {
                bn0.q = wp[((kb + 1) * 4 + 0) * 64];
                bn1.q = wp[((kb + 1) * 4 + 1) * 64];
                bn2.q = wp[((kb + 1) * 4 + 2) * 64];
                bn3.q = wp[((kb + 1) * 4 + 3) * 64];
            }
            FragU a;
            a.u[0] = pack_bf16_rne(xv[kb][0][0], xv[kb][0][1]);
            a.u[1] = pack_bf16_rne(xv[kb][0][2], xv[kb][0][3]);
            a.u[2] = pack_bf16_rne(xv[kb][1][0], xv[kb][1][1]);
            a.u[3] = pack_bf16_rne(xv[kb][1][2], xv[kb][1][3]);
            acc[0] = __builtin_amdgcn_mfma_f32_16x16x32_bf16(a.v, bc0.v, acc[0], 0, 0, 0);
            acc[1] = __builtin_amdgcn_mfma_f32_16x16x32_bf16(a.v, bc1.v, acc[1], 0, 0, 0);
            acc[2] = __builtin_amdgcn_mfma_f32_16x16x32_bf16(a.v, bc2.v, acc[2], 0, 0, 0);
            acc[3] = __builtin_amdgcn_mfma_f32_16x16x32_bf16(a.v, bc3.v, acc[3], 0, 0, 0);
            if (kb < 7) {
                bc0 = bn0;
                bc1 = bn1;
                bc2 = bn2;
                bc3 = bn3;
            }
        }

        const long long orow0 = (long long)bb * 64 + wv * 16 + quad * 4;
#pragma unroll
        for (int r = 0; r < 4; r++) {
            const long long orow = orow0 + r;
            if (orow < N) {
#pragma unroll
                for (int nt = 0; nt < 4; nt++) {
                    float v = acc[nt][r];  // UNscaled h
                    unsigned uv = __float_as_uint(v);
                    uv = (uv + 0x7FFFu + ((uv >> 16) & 1u)) >> 16;
                    g[orow * 64 + nt * 16 + l15] = (unsigned short)uv;
                }
            }
        }
    }
}

// ---------------------------------------------------------------------------
// CSR finish: per-bucket exclusive base, per-node degree (+self-loop), dinv,
// and the scatter of bucketed edges into final CSR order.
__global__ __launch_bounds__(WG) void k_csr(const unsigned* __restrict__ ebuf, const int* __restrict__ cursor,
                                            int* __restrict__ off, int* __restrict__ srcs,
                                            float* __restrict__ dinv, int N, int nbuse) {
    __shared__ int red[256];
    __shared__ int h[256];
    __shared__ int sc[256];
    __shared__ int cur[256];
    const int t = threadIdx.x;
    const int b = blockIdx.x;
    const int node0 = b << BSH;
    const int rows = min(256, N - node0);
    int part = 0;
    for (int i = t; i < b; i += WG) part += min(cursor[i], CAP);
    red[t] = part;
    h[t] = 0;
    __syncthreads();
    for (int d = WG / 2; d > 0; d >>= 1) {
        if (t < d) red[t] += red[t + d];
        __syncthreads();
    }
    const int ebase = red[0];
    const int cnt = min(cursor[b], CAP);
    const unsigned* eb = ebuf + (size_t)b * CAP;
    for (int j = t; j < cnt; j += WG) atomicAdd(&h[eb[j] >> 24], 1);
    __syncthreads();
    const int deg = (t < rows) ? h[t] + 1 : 0;  // +1 self-loop
    sc[t] = deg;
    __syncthreads();
    for (int d = 1; d < 256; d <<= 1) {
        int a = (t >= d) ? sc[t - d] : 0;
        __syncthreads();
        sc[t] += a;
        __syncthreads();
    }
    const int basef = ebase + node0;  // prior edges + prior self-loops
    const int local = sc[t] - deg;
    if (t < rows) {
        off[node0 + t] = basef + local;
        srcs[basef + local] = node0 + t;  // self-loop at slot 0
        cur[t] = local + 1;
        dinv[node0 + t] = rsqrtf((float)deg);
    }
    if (b == nbuse - 1 && t == 0) off[N] = ebase + cnt + N;
    __syncthreads();
    for (int j = t; j < cnt; j += WG) {
        unsigned w = eb[j];
        int dl = (int)(w >> 24);
        int pos = basef + atomicAdd(&cur[dl], 1);
        srcs[pos] = (int)(w & 0xFFFFFFu);
    }
}

// ---------------------------------------------------------------------------
// Gather: THIRTY-TWO lanes per dst node (2 nodes/wave). The four 8-lane
// sub-groups accumulate edge indices j = sub, sub+4, sub+8, ... - quartering
// the serial dependent chain (~17 -> ~4.3 iterations). R8 measured the 2-way
// split at ~+8 us total; same mechanism (chain > what 1-ahead prefetch can
// cover), one more level. Each quarter keeps srcs 1-ahead + dinv/row
// prefetch; merge = shfl_xor(8) + shfl_xor(16).
__global__ __launch_bounds__(WG) void k_gather(const unsigned short* __restrict__ g,
                                               const int* __restrict__ off, const int* __restrict__ srcs,
                                               const float* __restrict__ dinv, const float* __restrict__ bias,
                                               float* __restrict__ out, int N) {
    const int t = threadIdx.x;
    const int node = blockIdx.x * 8 + (t >> 5);
    if (node >= N) return;
    const int sub = (t >> 3) & 3;  // 0..3: edge-index residue class
    const int c8 = (t & 7) * 8;    // cols c8 .. c8+7
    const int e0 = off[node], e1 = off[node + 1];
    float a0 = 0.f, a1 = 0.f, a2 = 0.f, a3 = 0.f, a4 = 0.f, a5 = 0.f, a6 = 0.f, a7 = 0.f;

    int e = e0 + sub;  // this quarter walks e, e+4, e+8, ...
    if (e < e1) {
        int s_cur = srcs[e];
        int en = e + 4;
        int s_nxt = (en < e1) ? srcs[en] : 0;
        float ds = dinv[s_cur];
        uint4 v = *(const uint4*)(g + (long long)s_cur * 64 + c8);
        for (;;) {
            const bool more = en < e1;
            float dsn = 0.f;
            uint4 vn = v;
            int s2 = 0;
            if (more) {  // next edge's dependent loads issue under the FMAs
                dsn = dinv[s_nxt];
                vn = *(const uint4*)(g + (long long)s_nxt * 64 + c8);
            }
            const int en2 = en + 4;
            if (en2 < e1) s2 = srcs[en2];  // srcs one further ahead
            a0 += ds * __uint_as_float(v.x << 16);
            a1 += ds * __uint_as_float(v.x & 0xFFFF0000u);
            a2 += ds * __uint_as_float(v.y << 16);
            a3 += ds * __uint_as_float(v.y & 0xFFFF0000u);
            a4 += ds * __uint_as_float(v.z << 16);
            a5 += ds * __uint_as_float(v.z & 0xFFFF0000u);
            a6 += ds * __uint_as_float(v.w << 16);
            a7 += ds * __uint_as_float(v.w & 0xFFFF0000u);
            if (!more) break;
            ds = dsn;
            v = vn;
            s_nxt = s2;
            en = en2;
        }
    }

    // merge the four quarters: xor-8 pairs sub 0<->1 / 2<->3, xor-16 merges
    a0 += __shfl_xor(a0, 8, 64);
    a1 += __shfl_xor(a1, 8, 64);
    a2 += __shfl_xor(a2, 8, 64);
    a3 += __shfl_xor(a3, 8, 64);
    a4 += __shfl_xor(a4, 8, 64);
    a5 += __shfl_xor(a5, 8, 64);
    a6 += __shfl_xor(a6, 8, 64);
    a7 += __shfl_xor(a7, 8, 64);
    a0 += __shfl_xor(a0, 16, 64);
    a1 += __shfl_xor(a1, 16, 64);
    a2 += __shfl_xor(a2, 16, 64);
    a3 += __shfl_xor(a3, 16, 64);
    a4 += __shfl_xor(a4, 16, 64);
    a5 += __shfl_xor(a5, 16, 64);
    a6 += __shfl_xor(a6, 16, 64);
    a7 += __shfl_xor(a7, 16, 64);

    if (sub == 0) {
        const float d = dinv[node];
        const floatx4 b0 = *(const floatx4*)(bias + c8);
        const floatx4 b1 = *(const floatx4*)(bias + c8 + 4);
        floatx4 o0, o1;
        o0[0] = d * a0 + b0[0];
        o0[1] = d * a1 + b0[1];
        o0[2] = d * a2 + b0[2];
        o0[3] = d * a3 + b0[3];
        o1[0] = d * a4 + b1[0];
        o1[1] = d * a5 + b1[1];
        o1[2] = d * a6 + b1[2];
        o1[3] = d * a7 + b1[3];
        *(floatx4*)(out + (long long)node * 64 + c8) = o0;
        *(floatx4*)(out + (long long)node * 64 + c8 + 4) = o1;
    }
}

extern "C" void kernel_launch(void* const* d_in, const int* in_sizes, int n_in,
                              void* d_out, int out_size, void* d_ws, size_t ws_size,
                              hipStream_t stream) {
    const float* x = (const float*)d_in[0];
    const void* ei = d_in[1];
    const float* W = (const float*)d_in[2];
    const float* b = (const float*)d_in[3];
    float* out = (float*)d_out;

    const int N = in_sizes[0] / 256;  // requires N < 2^24 and N <= 131072 (here 100000)
    const int E = in_sizes[1] / 2;
    const int NBUSE = (N + 255) >> BSH;       // 391 buckets used
    const int GEMMB = (N + 63) / 64;          // 1563 gemm blocks

    char* ws = (char*)d_ws;
    size_t o = 0;
    auto alloc = [&](size_t bytes) -> void* {
        void* p = ws + o;
        o += (bytes + 255) & ~(size_t)255;
        return p;
    };
    float* dinv = (float*)alloc((size_t)N * 4);
    unsigned short* g = (unsigned short*)alloc((size_t)N * 64 * 2);   // bf16 h, 12.8 MB
    unsigned* ebuf = (unsigned*)alloc((size_t)NBUCK * CAP * 4);       // bucketed edges, 16.8 MB
    int* cursor = (int*)alloc((size_t)NBUCK * 4);                     // unpadded (32 lines)
    int* off = (int*)alloc((size_t)(N + 1) * 4);                      // final CSR offsets
    int* srcs = (int*)alloc((size_t)(E + N) * 4);                     // final CSR srcs (+self-loops)
    uint4* wpack = (uint4*)alloc((size_t)2048 * 16);                  // frag-layout bf16 W, 32 KB
    if (o > ws_size) return;  // fail visibly rather than corrupt

    k_packw<<<8, WG, 0, stream>>>(W, wpack, cursor);
    k_main<<<EBLK + GEMMB, WG, 0, stream>>>(ei, cursor, ebuf, E, x, wpack, g, N);
    k_csr<<<NBUSE, WG, 0, stream>>>(ebuf, cursor, off, srcs, dinv, N, NBUSE);
    k_gather<<<(N + 7) / 8, WG, 0, stream>>>(g, off, srcs, dinv, b, out, N);
}